// Round 2
// baseline (352.599 us; speedup 1.0000x reference)
//
#include <hip/hip_runtime.h>

// out[row] = (sum_{f<1024} x[row,f]) * (sum coeffs), rows = 16*4096 = 65536.
// Pure streaming reduction: 256 MiB read, 256 KiB write -> HBM-bound,
// floor ~43 us at 6.3 TB/s achievable.
//
// R2 = R1 resubmitted verbatim (R1 bench died on container infra, no data).
// Change vs previous 329.9us best: drop __builtin_nontemporal_load (nt/sc
// bits force cache-bypassing reads; measured kernel BW was only ~1.6 TB/s
// while the harness fill kernel hit 6.6 TB/s on the same graph). Plain
// cached global_load_dwordx4 should restore streaming-read efficiency.
//
// Structure: 2048 blocks x 256 threads = 8192 waves (8 blocks/CU, full
// 32-wave occupancy). Each wave owns rows {w + i*8192}, processed 2 rows
// per loop iteration -> 8 independent float4 loads in flight before the
// shuffle reduction (which is off the load critical path).

typedef float vf4 __attribute__((ext_vector_type(4)));

#define WAVES_PER_BLOCK 4
#define NUM_BLOCKS 2048

__global__ __launch_bounds__(256) void spline_rowsum_kernel(
    const float* __restrict__ x,
    const float* __restrict__ coeffs,
    float* __restrict__ out,
    int nrows) {
  const int lane = threadIdx.x & 63;
  const int w = blockIdx.x * WAVES_PER_BLOCK + (threadIdx.x >> 6);
  const int total_waves = NUM_BLOCKS * WAVES_PER_BLOCK;  // 8192

  float cs = 0.0f;
#pragma unroll
  for (int k = 0; k < 10; ++k) cs += coeffs[k];  // scalar, L2-resident

  int r = w;
  // main loop: 2 rows per iteration, 8 x 16B loads outstanding
  for (; r + total_waves < nrows; r += 2 * total_waves) {
    const vf4* xa = reinterpret_cast<const vf4*>(x + (long long)r * 1024) + lane;
    const vf4* xb = reinterpret_cast<const vf4*>(
                        x + (long long)(r + total_waves) * 1024) + lane;

    vf4 a0 = xa[0 * 64];
    vf4 a1 = xa[1 * 64];
    vf4 a2 = xa[2 * 64];
    vf4 a3 = xa[3 * 64];
    vf4 b0 = xb[0 * 64];
    vf4 b1 = xb[1 * 64];
    vf4 b2 = xb[2 * 64];
    vf4 b3 = xb[3 * 64];

    float sa = ((a0.x + a0.y) + (a0.z + a0.w)) + ((a1.x + a1.y) + (a1.z + a1.w))
             + ((a2.x + a2.y) + (a2.z + a2.w)) + ((a3.x + a3.y) + (a3.z + a3.w));
    float sb = ((b0.x + b0.y) + (b0.z + b0.w)) + ((b1.x + b1.y) + (b1.z + b1.w))
             + ((b2.x + b2.y) + (b2.z + b2.w)) + ((b3.x + b3.y) + (b3.z + b3.w));

#pragma unroll
    for (int off = 32; off > 0; off >>= 1) {
      sa += __shfl_down(sa, off, 64);
      sb += __shfl_down(sb, off, 64);
    }
    if (lane == 0) {
      out[r] = sa * cs;
      out[r + total_waves] = sb * cs;
    }
  }
  // tail: at most one row left for this wave
  if (r < nrows) {
    const vf4* xa = reinterpret_cast<const vf4*>(x + (long long)r * 1024) + lane;
    vf4 a0 = xa[0 * 64];
    vf4 a1 = xa[1 * 64];
    vf4 a2 = xa[2 * 64];
    vf4 a3 = xa[3 * 64];
    float sa = ((a0.x + a0.y) + (a0.z + a0.w)) + ((a1.x + a1.y) + (a1.z + a1.w))
             + ((a2.x + a2.y) + (a2.z + a2.w)) + ((a3.x + a3.y) + (a3.z + a3.w));
#pragma unroll
    for (int off = 32; off > 0; off >>= 1) sa += __shfl_down(sa, off, 64);
    if (lane == 0) out[r] = sa * cs;
  }
}

extern "C" void kernel_launch(void* const* d_in, const int* in_sizes, int n_in,
                              void* d_out, int out_size, void* d_ws, size_t ws_size,
                              hipStream_t stream) {
  const float* x      = (const float*)d_in[0];   // 16*4096*1024 fp32
  const float* coeffs = (const float*)d_in[1];   // 10 fp32
  float* out          = (float*)d_out;           // 65536 fp32

  spline_rowsum_kernel<<<NUM_BLOCKS, 256, 0, stream>>>(x, coeffs, out, out_size);
}

// Round 3
// 329.342 us; speedup vs baseline: 1.0706x; 1.0706x over previous
//
#include <hip/hip_runtime.h>

// out[row] = (sum_{f<1024} x[row,f]) * (sum coeffs), rows = 16*4096 = 65536.
// Pure streaming reduction: 256 MiB read, 256 KiB write -> HBM-bound,
// floor ~43 us at 6.3 TB/s achievable.
//
// R3 fix: previous kernels passed out_size (BYTES = 262144) as nrows ->
// processed 262144 rows = 1 GiB of reads (768 MiB OOB into allocator slack),
// 4x the necessary traffic, at full nt-load roofline (6.35 TB/s). Both prior
// rounds decompose exactly as fill(~160us) + 1GiB-stream. Fix: hardcode
// NROWS=65536 (fixed problem shape; out_size unit is ambiguous -> never
// derive the loop bound from it).
// Also revert to nontemporal loads: R2 measured cached streaming reads at
// 5.5 TB/s vs nt 6.35 TB/s on the same stream (+13% for nt).
//
// Structure: 2048 blocks x 256 threads = 8192 waves (8 blocks/CU, full
// 32-wave occupancy). Each wave owns rows {w + i*8192}, 2 rows per loop
// iteration -> 8 x 16B nt loads in flight before the shuffle reduction
// (which is off the load critical path). 65536/8192 = 8 rows/wave,
// 4 main-loop iterations, no tail.

typedef float vf4 __attribute__((ext_vector_type(4)));

#define WAVES_PER_BLOCK 4
#define NUM_BLOCKS 2048
#define NROWS 65536

__global__ __launch_bounds__(256) void spline_rowsum_kernel(
    const float* __restrict__ x,
    const float* __restrict__ coeffs,
    float* __restrict__ out) {
  const int lane = threadIdx.x & 63;
  const int w = blockIdx.x * WAVES_PER_BLOCK + (threadIdx.x >> 6);
  const int total_waves = NUM_BLOCKS * WAVES_PER_BLOCK;  // 8192

  float cs = 0.0f;
#pragma unroll
  for (int k = 0; k < 10; ++k) cs += coeffs[k];  // scalar, L2-resident

  int r = w;
  // main loop: 2 rows per iteration, 8 x 16B loads outstanding
  for (; r + total_waves < NROWS; r += 2 * total_waves) {
    const vf4* xa = reinterpret_cast<const vf4*>(x + (long long)r * 1024) + lane;
    const vf4* xb = reinterpret_cast<const vf4*>(
                        x + (long long)(r + total_waves) * 1024) + lane;

    vf4 a0 = __builtin_nontemporal_load(xa + 0 * 64);
    vf4 a1 = __builtin_nontemporal_load(xa + 1 * 64);
    vf4 a2 = __builtin_nontemporal_load(xa + 2 * 64);
    vf4 a3 = __builtin_nontemporal_load(xa + 3 * 64);
    vf4 b0 = __builtin_nontemporal_load(xb + 0 * 64);
    vf4 b1 = __builtin_nontemporal_load(xb + 1 * 64);
    vf4 b2 = __builtin_nontemporal_load(xb + 2 * 64);
    vf4 b3 = __builtin_nontemporal_load(xb + 3 * 64);

    float sa = ((a0.x + a0.y) + (a0.z + a0.w)) + ((a1.x + a1.y) + (a1.z + a1.w))
             + ((a2.x + a2.y) + (a2.z + a2.w)) + ((a3.x + a3.y) + (a3.z + a3.w));
    float sb = ((b0.x + b0.y) + (b0.z + b0.w)) + ((b1.x + b1.y) + (b1.z + b1.w))
             + ((b2.x + b2.y) + (b2.z + b2.w)) + ((b3.x + b3.y) + (b3.z + b3.w));

#pragma unroll
    for (int off = 32; off > 0; off >>= 1) {
      sa += __shfl_down(sa, off, 64);
      sb += __shfl_down(sb, off, 64);
    }
    if (lane == 0) {
      out[r] = sa * cs;
      out[r + total_waves] = sb * cs;
    }
  }
  // tail: at most one row left for this wave (not taken for 65536/8192=8 rows)
  if (r < NROWS) {
    const vf4* xa = reinterpret_cast<const vf4*>(x + (long long)r * 1024) + lane;
    vf4 a0 = __builtin_nontemporal_load(xa + 0 * 64);
    vf4 a1 = __builtin_nontemporal_load(xa + 1 * 64);
    vf4 a2 = __builtin_nontemporal_load(xa + 2 * 64);
    vf4 a3 = __builtin_nontemporal_load(xa + 3 * 64);
    float sa = ((a0.x + a0.y) + (a0.z + a0.w)) + ((a1.x + a1.y) + (a1.z + a1.w))
             + ((a2.x + a2.y) + (a2.z + a2.w)) + ((a3.x + a3.y) + (a3.z + a3.w));
#pragma unroll
    for (int off = 32; off > 0; off >>= 1) sa += __shfl_down(sa, off, 64);
    if (lane == 0) out[r] = sa * cs;
  }
}

extern "C" void kernel_launch(void* const* d_in, const int* in_sizes, int n_in,
                              void* d_out, int out_size, void* d_ws, size_t ws_size,
                              hipStream_t stream) {
  const float* x      = (const float*)d_in[0];   // 16*4096*1024 fp32
  const float* coeffs = (const float*)d_in[1];   // 10 fp32
  float* out          = (float*)d_out;           // 65536 fp32

  spline_rowsum_kernel<<<NUM_BLOCKS, 256, 0, stream>>>(x, coeffs, out);
}